// Round 3
// baseline (815.066 us; speedup 1.0000x reference)
//
#include <hip/hip_runtime.h>
#include <math.h>

typedef unsigned short u16;
typedef unsigned int u32;
typedef short bf16x8 __attribute__((ext_vector_type(8)));
typedef float f32x4 __attribute__((ext_vector_type(4)));
typedef u16 u16x4 __attribute__((ext_vector_type(4)));
typedef u16 u16x8 __attribute__((ext_vector_type(8)));
typedef u32 u32x4 __attribute__((ext_vector_type(4)));

// ---------- bf16 <-> f32 helpers ----------
static __device__ __forceinline__ float b2f(u16 u) {
  union { u32 i; float f; } v; v.i = ((u32)u) << 16; return v.f;
}
static __device__ __forceinline__ float blo(u32 u) {
  union { u32 i; float f; } v; v.i = u << 16; return v.f;
}
static __device__ __forceinline__ float bhi(u32 u) {
  union { u32 i; float f; } v; v.i = u & 0xffff0000u; return v.f;
}
static __device__ __forceinline__ u16 f2b(float f) {
  union { float f; u32 i; } v; v.f = f;
  u32 r = v.i + 0x7fffu + ((v.i >> 16) & 1u);
  return (u16)(r >> 16);
}

// ---------- async global -> LDS, 16B per lane (bf16 tiles) ----------
static __device__ __forceinline__ void g2l16(const void* g, void* l) {
  typedef __attribute__((address_space(1))) const void gvoid;
  typedef __attribute__((address_space(3))) void lvoid;
  __builtin_amdgcn_global_load_lds((gvoid*)g, (lvoid*)l, 16, 0, 0);
}

// =====================================================================
// LayerNorm: rows 0..8191 -> x_feat (from x), rows 8192..9215 -> x_motion
// (from motion_vec). C = 3072, no affine. fp32 in -> bf16 out (internal).
// =====================================================================
__global__ __launch_bounds__(256)
void ln_kernel(const float* __restrict__ x, const float* __restrict__ mv,
               u16* __restrict__ xf, u16* __restrict__ xm)
{
  const int row = blockIdx.x, tid = threadIdx.x;
  const float* src; u16* dst;
  if (row < 8192) { src = x + (size_t)row * 3072;          dst = xf + (size_t)row * 3072; }
  else            { src = mv + (size_t)(row - 8192) * 3072; dst = xm + (size_t)(row - 8192) * 3072; }

  f32x4 vals[3];
  #pragma unroll
  for (int i = 0; i < 3; ++i) vals[i] = *(const f32x4*)(src + tid * 4 + i * 1024);

  float s1 = 0.f, s2 = 0.f;
  #pragma unroll
  for (int i = 0; i < 3; ++i) {
    f32x4 v = vals[i];
    s1 += v.x + v.y + v.z + v.w;
    s2 += v.x * v.x + v.y * v.y + v.z * v.z + v.w * v.w;
  }
  #pragma unroll
  for (int o = 32; o > 0; o >>= 1) { s1 += __shfl_down(s1, o); s2 += __shfl_down(s2, o); }
  __shared__ float r1[4], r2[4];
  const int wv = tid >> 6, ln = tid & 63;
  if (ln == 0) { r1[wv] = s1; r2[wv] = s2; }
  __syncthreads();
  const float t1 = r1[0] + r1[1] + r1[2] + r1[3];
  const float t2 = r2[0] + r2[1] + r2[2] + r2[3];
  const float mu = t1 * (1.f / 3072.f);
  const float rs = rsqrtf(t2 * (1.f / 3072.f) - mu * mu + 1e-6f);
  #pragma unroll
  for (int i = 0; i < 3; ++i) {
    f32x4 v = vals[i]; u16x4 w;
    w.x = f2b((v.x - mu) * rs); w.y = f2b((v.y - mu) * rs);
    w.z = f2b((v.z - mu) * rs); w.w = f2b((v.w - mu) * rs);
    *(u16x4*)(dst + tid * 4 + i * 1024) = w;
  }
}

// =====================================================================
// GEMM: C[M,N] = A[M,K] @ W[N,K]^T + bias[N]
//   A: internal bf16 (global_load_lds staging, m97 structure)
//   W: external fp32, reg-staged + converted to bf16 LDS tile
//   C: TOUT = u16 (internal bf16) or float (final output)
// 128x128 tile, BK=32, 4 waves (2x2), mfma_f32_16x16x32_bf16.
// EPI==1: multiply row-wise by fp32 mask[row].
// =====================================================================
template<int EPI, typename TOUT>
__global__ __launch_bounds__(256)
void gemm_kernel(const u16* __restrict__ A, const float* __restrict__ W,
                 const float* __restrict__ bias, const float* __restrict__ mask,
                 TOUT* __restrict__ C, int M, int N, int K)
{
  __shared__ __align__(16) u16 lA[4096];
  __shared__ __align__(16) u16 lB[4096];
  const int tid = threadIdx.x, wave = tid >> 6, lane = tid & 63;
  const int nbx = N >> 7;
  const int brow = (blockIdx.x / nbx) << 7;
  const int bcol = (blockIdx.x % nbx) << 7;
  const int wr = wave >> 1, wc = wave & 1;

  f32x4 acc[4][4] = {};
  const u16* gA = A + (size_t)brow * K;
  const float* gB = W + (size_t)bcol * K;

  // fp32 B staging coords (fixed per thread): 16 floats each
  const int br = tid >> 1, bk0 = (tid & 1) << 4;
  const float* bsrc0 = gB + (size_t)br * K + bk0;
  u16* bdst = &lB[br * 32 + bk0];

  for (int tk = 0; tk < K; tk += 32) {
    // A tile 128x32 bf16 (8 KB): 512 x 16B chunks, wave-uniform LDS base
    #pragma unroll
    for (int j = 0; j < 2; ++j) {
      const int c = j * 256 + wave * 64 + lane;
      const int r = c >> 2, k8 = (c & 3) << 3;
      g2l16(gA + (size_t)r * K + tk + k8, (char*)lA + (size_t)(j * 256 + wave * 64) * 16);
    }
    // B tile: each thread loads 16 fp32, converts, writes bf16 to LDS
    {
      const float* src = bsrc0 + tk;
      #pragma unroll
      for (int j = 0; j < 4; ++j) {
        f32x4 v = *(const f32x4*)(src + 4 * j);
        u16x4 w; w.x = f2b(v.x); w.y = f2b(v.y); w.z = f2b(v.z); w.w = f2b(v.w);
        *(u16x4*)(bdst + 4 * j) = w;
      }
    }
    __syncthreads();

    bf16x8 af[4], bfr[4];
    #pragma unroll
    for (int m = 0; m < 4; ++m)
      af[m] = *(const bf16x8*)&lA[(wr * 64 + m * 16 + (lane & 15)) * 32 + ((lane >> 4) << 3)];
    #pragma unroll
    for (int n = 0; n < 4; ++n)
      bfr[n] = *(const bf16x8*)&lB[(wc * 64 + n * 16 + (lane & 15)) * 32 + ((lane >> 4) << 3)];
    #pragma unroll
    for (int m = 0; m < 4; ++m)
      #pragma unroll
      for (int n = 0; n < 4; ++n)
        acc[m][n] = __builtin_amdgcn_mfma_f32_16x16x32_bf16(af[m], bfr[n], acc[m][n], 0, 0, 0);
    __syncthreads();
  }

  // epilogue: D row = 4*(lane>>4)+i, col = lane&15 (m89-verified layout)
  #pragma unroll
  for (int m = 0; m < 4; ++m) {
    const int row = brow + wr * 64 + m * 16 + ((lane >> 4) << 2);
    #pragma unroll
    for (int n = 0; n < 4; ++n) {
      const int col = bcol + wc * 64 + n * 16 + (lane & 15);
      const float bv = bias[col];
      #pragma unroll
      for (int i = 0; i < 4; ++i) {
        float v = acc[m][n][i] + bv;
        if (EPI == 1) v *= mask[row + i];
        if constexpr (__is_same(TOUT, u16))
          C[(size_t)(row + i) * N + col] = f2b(v);
        else
          C[(size_t)(row + i) * N + col] = v;
      }
    }
  }
}

// =====================================================================
// Attention per (b,t,h): Q(256x128) x K(32x128)^T -> softmax -> x V.
// q-rmsnorm per row; k-rmsnorm + q_norm_w*k_norm_w folded into staged K.
// qb/kvb/out internal bf16; qw/kw external fp32.
// =====================================================================
__global__ __launch_bounds__(256)
void attn_kernel(const u16* __restrict__ qb, const u16* __restrict__ kvb,
                 const float* __restrict__ qw, const float* __restrict__ kw,
                 u16* __restrict__ attnb)
{
  __shared__ __align__(16) float Ks[32][128];
  __shared__ __align__(16) u32 Vsu[32][64];
  __shared__ float scL[256 * 33];
  const int tid = threadIdx.x;
  const int h = blockIdx.x % 24;
  const int bt = blockIdx.x / 24;

  { // stage K (rmsnorm + folded q/k norm weights) and V: 8 threads/row
    const int n = tid >> 3, sub = tid & 7;
    const size_t base = (size_t)(bt * 32 + n) * 6144 + (size_t)h * 128;
    const u16* kp = kvb + base + sub * 16;
    const u16* vp = kvb + base + 3072 + sub * 16;
    float kv_[16]; float ss = 0.f;
    u16x8 k0 = *(const u16x8*)kp;
    u16x8 k1 = *(const u16x8*)(kp + 8);
    #pragma unroll
    for (int j = 0; j < 8; ++j) { kv_[j] = b2f(k0[j]); kv_[8 + j] = b2f(k1[j]); }
    #pragma unroll
    for (int j = 0; j < 16; ++j) ss += kv_[j] * kv_[j];
    ss += __shfl_xor(ss, 1); ss += __shfl_xor(ss, 2); ss += __shfl_xor(ss, 4);
    const float krs = rsqrtf(ss * (1.f / 128.f) + 1e-6f);
    #pragma unroll
    for (int j = 0; j < 16; ++j) {
      const int d = sub * 16 + j;
      Ks[n][d] = kv_[j] * krs * kw[d] * qw[d];
    }
    u32x4 v0 = *(const u32x4*)vp;
    u32x4 v1 = *(const u32x4*)(vp + 8);
    #pragma unroll
    for (int j = 0; j < 4; ++j) { Vsu[n][sub * 8 + j] = v0[j]; Vsu[n][sub * 8 + 4 + j] = v1[j]; }
  }
  __syncthreads();

  // per-thread query row
  const u16* qp = qb + (size_t)(bt * 256 + tid) * 3072 + (size_t)h * 128;
  u32 qr[64]; float qss = 0.f;
  #pragma unroll
  for (int i = 0; i < 16; ++i) {
    u32x4 t = ((const u32x4*)qp)[i];
    qr[4 * i + 0] = t.x; qr[4 * i + 1] = t.y; qr[4 * i + 2] = t.z; qr[4 * i + 3] = t.w;
  }
  #pragma unroll
  for (int i = 0; i < 64; ++i) { const float a = blo(qr[i]), b = bhi(qr[i]); qss += a * a + b * b; }
  const float qsc = rsqrtf(qss * (1.f / 128.f) + 1e-6f) * 0.08838834764831845f; // * 1/sqrt(D)

  float* mysc = &scL[tid * 33];
  for (int n2 = 0; n2 < 32; ++n2) {
    const f32x4* kr = (const f32x4*)&Ks[n2][0];
    float dot = 0.f;
    #pragma unroll
    for (int dd = 0; dd < 32; ++dd) {
      const f32x4 kk = kr[dd];
      const u32 a0 = qr[2 * dd], a1 = qr[2 * dd + 1];
      dot += blo(a0) * kk.x + bhi(a0) * kk.y + blo(a1) * kk.z + bhi(a1) * kk.w;
    }
    mysc[n2] = dot * qsc;
  }

  float p[32];
  #pragma unroll
  for (int j = 0; j < 32; ++j) p[j] = mysc[j];
  float mx = p[0];
  #pragma unroll
  for (int j = 1; j < 32; ++j) mx = fmaxf(mx, p[j]);
  float se = 0.f;
  #pragma unroll
  for (int j = 0; j < 32; ++j) { p[j] = expf(p[j] - mx); se += p[j]; }
  const float inv = 1.f / se;
  #pragma unroll
  for (int j = 0; j < 32; ++j) mysc[j] = p[j] * inv;

  u16* op = attnb + (size_t)(bt * 256 + tid) * 3072 + (size_t)h * 128;
  for (int db = 0; db < 16; ++db) {
    float o[8] = {0.f, 0.f, 0.f, 0.f, 0.f, 0.f, 0.f, 0.f};
    for (int n2 = 0; n2 < 32; ++n2) {
      const u32x4 vv = *(const u32x4*)&Vsu[n2][db * 4];
      const float pp = mysc[n2];
      o[0] += pp * blo(vv.x); o[1] += pp * bhi(vv.x);
      o[2] += pp * blo(vv.y); o[3] += pp * bhi(vv.y);
      o[4] += pp * blo(vv.z); o[5] += pp * bhi(vv.z);
      o[6] += pp * blo(vv.w); o[7] += pp * bhi(vv.w);
    }
    u16x8 w;
    #pragma unroll
    for (int j = 0; j < 8; ++j) w[j] = f2b(o[j]);
    *(u16x8*)(op + db * 8) = w;
  }
}

// =====================================================================
extern "C" void kernel_launch(void* const* d_in, const int* in_sizes, int n_in,
                              void* d_out, int out_size, void* d_ws, size_t ws_size,
                              hipStream_t stream) {
  const float* x    = (const float*)d_in[0];
  const float* mv   = (const float*)d_in[1];
  const float* mask = (const float*)d_in[2];
  const float* wkv  = (const float*)d_in[3];
  const float* bkv  = (const float*)d_in[4];
  const float* wq   = (const float*)d_in[5];
  const float* bq   = (const float*)d_in[6];
  const float* wo   = (const float*)d_in[7];
  const float* bo   = (const float*)d_in[8];
  const float* qnw  = (const float*)d_in[9];
  const float* knw  = (const float*)d_in[10];
  float* out = (float*)d_out;

  // workspace layout (119.5 MB); attn output reuses the xf slab
  char* ws = (char*)d_ws;
  u16* xf   = (u16*)(ws);                 // 8192x3072 bf16 = 50,331,648 B
  u16* xm   = (u16*)(ws + 50331648);      // 1024x3072 bf16 =  6,291,456 B
  u16* qbuf = (u16*)(ws + 56623104);      // 8192x3072 bf16 = 50,331,648 B
  u16* kvb  = (u16*)(ws + 106954752);     // 1024x6144 bf16 = 12,582,912 B (end 119,537,664)

  ln_kernel<<<9216, 256, 0, stream>>>(x, mv, xf, xm);
  gemm_kernel<0, u16><<<1536, 256, 0, stream>>>(xf, wq, bq, nullptr, qbuf, 8192, 3072, 3072);
  gemm_kernel<0, u16><<<384, 256, 0, stream>>>(xm, wkv, bkv, nullptr, kvb, 1024, 6144, 3072);
  attn_kernel<<<768, 256, 0, stream>>>(qbuf, kvb, qnw, knw, xf);
  gemm_kernel<1, float><<<1536, 256, 0, stream>>>(xf, wo, bo, mask, out, 8192, 3072, 3072);
}

// Round 4
// 665.940 us; speedup vs baseline: 1.2239x; 1.2239x over previous
//
#include <hip/hip_runtime.h>
#include <math.h>

typedef unsigned short u16;
typedef unsigned int u32;
typedef short bf16x8 __attribute__((ext_vector_type(8)));
typedef float f32x4 __attribute__((ext_vector_type(4)));
typedef u16 u16x4 __attribute__((ext_vector_type(4)));
typedef u16 u16x8 __attribute__((ext_vector_type(8)));
typedef u32 u32x4 __attribute__((ext_vector_type(4)));

// ---------- bf16 <-> f32 helpers ----------
static __device__ __forceinline__ float b2f(u16 u) {
  union { u32 i; float f; } v; v.i = ((u32)u) << 16; return v.f;
}
static __device__ __forceinline__ float blo(u32 u) {
  union { u32 i; float f; } v; v.i = u << 16; return v.f;
}
static __device__ __forceinline__ float bhi(u32 u) {
  union { u32 i; float f; } v; v.i = u & 0xffff0000u; return v.f;
}
static __device__ __forceinline__ u16 f2b(float f) {
  union { float f; u32 i; } v; v.f = f;
  u32 r = v.i + 0x7fffu + ((v.i >> 16) & 1u);
  return (u16)(r >> 16);
}

// ---------- async global -> LDS, 16B per lane (bf16 tiles) ----------
static __device__ __forceinline__ void g2l16(const void* g, void* l) {
  typedef __attribute__((address_space(1))) const void gvoid;
  typedef __attribute__((address_space(3))) void lvoid;
  __builtin_amdgcn_global_load_lds((gvoid*)g, (lvoid*)l, 16, 0, 0);
}

// =====================================================================
// Weight convert: fp32 -> bf16, grid-stride, 4 elems/thread/iter.
// =====================================================================
__global__ __launch_bounds__(256)
void wcvt_kernel(const float* __restrict__ src, u16* __restrict__ dst, int n4)
{
  for (int i = blockIdx.x * 256 + threadIdx.x; i < n4; i += gridDim.x * 256) {
    f32x4 v = *(const f32x4*)(src + (size_t)i * 4);
    u16x4 w; w.x = f2b(v.x); w.y = f2b(v.y); w.z = f2b(v.z); w.w = f2b(v.w);
    *(u16x4*)(dst + (size_t)i * 4) = w;
  }
}

// =====================================================================
// LayerNorm: rows 0..8191 -> x_feat (from x), rows 8192..9215 -> x_motion
// (from motion_vec). C = 3072, no affine. fp32 in -> bf16 out (internal).
// =====================================================================
__global__ __launch_bounds__(256)
void ln_kernel(const float* __restrict__ x, const float* __restrict__ mv,
               u16* __restrict__ xf, u16* __restrict__ xm)
{
  const int row = blockIdx.x, tid = threadIdx.x;
  const float* src; u16* dst;
  if (row < 8192) { src = x + (size_t)row * 3072;          dst = xf + (size_t)row * 3072; }
  else            { src = mv + (size_t)(row - 8192) * 3072; dst = xm + (size_t)(row - 8192) * 3072; }

  f32x4 vals[3];
  #pragma unroll
  for (int i = 0; i < 3; ++i) vals[i] = *(const f32x4*)(src + tid * 4 + i * 1024);

  float s1 = 0.f, s2 = 0.f;
  #pragma unroll
  for (int i = 0; i < 3; ++i) {
    f32x4 v = vals[i];
    s1 += v.x + v.y + v.z + v.w;
    s2 += v.x * v.x + v.y * v.y + v.z * v.z + v.w * v.w;
  }
  #pragma unroll
  for (int o = 32; o > 0; o >>= 1) { s1 += __shfl_down(s1, o); s2 += __shfl_down(s2, o); }
  __shared__ float r1[4], r2[4];
  const int wv = tid >> 6, ln = tid & 63;
  if (ln == 0) { r1[wv] = s1; r2[wv] = s2; }
  __syncthreads();
  const float t1 = r1[0] + r1[1] + r1[2] + r1[3];
  const float t2 = r2[0] + r2[1] + r2[2] + r2[3];
  const float mu = t1 * (1.f / 3072.f);
  const float rs = rsqrtf(t2 * (1.f / 3072.f) - mu * mu + 1e-6f);
  #pragma unroll
  for (int i = 0; i < 3; ++i) {
    f32x4 v = vals[i]; u16x4 w;
    w.x = f2b((v.x - mu) * rs); w.y = f2b((v.y - mu) * rs);
    w.z = f2b((v.z - mu) * rs); w.w = f2b((v.w - mu) * rs);
    *(u16x4*)(dst + tid * 4 + i * 1024) = w;
  }
}

// =====================================================================
// Pure-bf16 GEMM (m97 structure): C[M,N] = A[M,K] @ Wb[N,K]^T + bias[N]
// A, Wb internal bf16, both staged via global_load_lds width=16.
// 128x128 tile, BK=32, 4 waves (2x2), mfma_f32_16x16x32_bf16.
// EPI==1: multiply row-wise by fp32 mask[row]. TOUT: u16 (bf16) or float.
// =====================================================================
template<int EPI, typename TOUT>
__global__ __launch_bounds__(256)
void gemm_bb(const u16* __restrict__ A, const u16* __restrict__ Wb,
             const float* __restrict__ bias, const float* __restrict__ mask,
             TOUT* __restrict__ C, int M, int N, int K)
{
  __shared__ __align__(16) u16 lA[4096];
  __shared__ __align__(16) u16 lB[4096];
  const int tid = threadIdx.x, wave = tid >> 6, lane = tid & 63;
  const int nbx = N >> 7;
  const int brow = (blockIdx.x / nbx) << 7;
  const int bcol = (blockIdx.x % nbx) << 7;
  const int wr = wave >> 1, wc = wave & 1;

  f32x4 acc[4][4] = {};
  const u16* gA = A + (size_t)brow * K;
  const u16* gB = Wb + (size_t)bcol * K;

  for (int tk = 0; tk < K; tk += 32) {
    #pragma unroll
    for (int j = 0; j < 2; ++j) {
      const int c = j * 256 + wave * 64 + lane;
      const int r = c >> 2, k8 = (c & 3) << 3;
      g2l16(gA + (size_t)r * K + tk + k8, (char*)lA + (size_t)(j * 256 + wave * 64) * 16);
      g2l16(gB + (size_t)r * K + tk + k8, (char*)lB + (size_t)(j * 256 + wave * 64) * 16);
    }
    __syncthreads();

    bf16x8 af[4], bfr[4];
    #pragma unroll
    for (int m = 0; m < 4; ++m)
      af[m] = *(const bf16x8*)&lA[(wr * 64 + m * 16 + (lane & 15)) * 32 + ((lane >> 4) << 3)];
    #pragma unroll
    for (int n = 0; n < 4; ++n)
      bfr[n] = *(const bf16x8*)&lB[(wc * 64 + n * 16 + (lane & 15)) * 32 + ((lane >> 4) << 3)];
    #pragma unroll
    for (int m = 0; m < 4; ++m)
      #pragma unroll
      for (int n = 0; n < 4; ++n)
        acc[m][n] = __builtin_amdgcn_mfma_f32_16x16x32_bf16(af[m], bfr[n], acc[m][n], 0, 0, 0);
    __syncthreads();
  }

  #pragma unroll
  for (int m = 0; m < 4; ++m) {
    const int row = brow + wr * 64 + m * 16 + ((lane >> 4) << 2);
    #pragma unroll
    for (int n = 0; n < 4; ++n) {
      const int col = bcol + wc * 64 + n * 16 + (lane & 15);
      const float bv = bias[col];
      #pragma unroll
      for (int i = 0; i < 4; ++i) {
        float v = acc[m][n][i] + bv;
        if (EPI == 1) v *= mask[row + i];
        if constexpr (__is_same(TOUT, u16))
          C[(size_t)(row + i) * N + col] = f2b(v);
        else
          C[(size_t)(row + i) * N + col] = v;
      }
    }
  }
}

// =====================================================================
// Fallback mixed GEMM (R3 path): W fp32, reg-staged cvt into LDS.
// Used only if ws_size is too small for the weight slab.
// =====================================================================
template<int EPI, typename TOUT>
__global__ __launch_bounds__(256)
void gemm_mixed(const u16* __restrict__ A, const float* __restrict__ W,
                const float* __restrict__ bias, const float* __restrict__ mask,
                TOUT* __restrict__ C, int M, int N, int K)
{
  __shared__ __align__(16) u16 lA[4096];
  __shared__ __align__(16) u16 lB[4096];
  const int tid = threadIdx.x, wave = tid >> 6, lane = tid & 63;
  const int nbx = N >> 7;
  const int brow = (blockIdx.x / nbx) << 7;
  const int bcol = (blockIdx.x % nbx) << 7;
  const int wr = wave >> 1, wc = wave & 1;

  f32x4 acc[4][4] = {};
  const u16* gA = A + (size_t)brow * K;
  const float* gB = W + (size_t)bcol * K;
  const int br = tid >> 1, bk0 = (tid & 1) << 4;
  const float* bsrc0 = gB + (size_t)br * K + bk0;
  u16* bdst = &lB[br * 32 + bk0];

  for (int tk = 0; tk < K; tk += 32) {
    #pragma unroll
    for (int j = 0; j < 2; ++j) {
      const int c = j * 256 + wave * 64 + lane;
      const int r = c >> 2, k8 = (c & 3) << 3;
      g2l16(gA + (size_t)r * K + tk + k8, (char*)lA + (size_t)(j * 256 + wave * 64) * 16);
    }
    {
      const float* src = bsrc0 + tk;
      #pragma unroll
      for (int j = 0; j < 4; ++j) {
        f32x4 v = *(const f32x4*)(src + 4 * j);
        u16x4 w; w.x = f2b(v.x); w.y = f2b(v.y); w.z = f2b(v.z); w.w = f2b(v.w);
        *(u16x4*)(bdst + 4 * j) = w;
      }
    }
    __syncthreads();

    bf16x8 af[4], bfr[4];
    #pragma unroll
    for (int m = 0; m < 4; ++m)
      af[m] = *(const bf16x8*)&lA[(wr * 64 + m * 16 + (lane & 15)) * 32 + ((lane >> 4) << 3)];
    #pragma unroll
    for (int n = 0; n < 4; ++n)
      bfr[n] = *(const bf16x8*)&lB[(wc * 64 + n * 16 + (lane & 15)) * 32 + ((lane >> 4) << 3)];
    #pragma unroll
    for (int m = 0; m < 4; ++m)
      #pragma unroll
      for (int n = 0; n < 4; ++n)
        acc[m][n] = __builtin_amdgcn_mfma_f32_16x16x32_bf16(af[m], bfr[n], acc[m][n], 0, 0, 0);
    __syncthreads();
  }

  #pragma unroll
  for (int m = 0; m < 4; ++m) {
    const int row = brow + wr * 64 + m * 16 + ((lane >> 4) << 2);
    #pragma unroll
    for (int n = 0; n < 4; ++n) {
      const int col = bcol + wc * 64 + n * 16 + (lane & 15);
      const float bv = bias[col];
      #pragma unroll
      for (int i = 0; i < 4; ++i) {
        float v = acc[m][n][i] + bv;
        if (EPI == 1) v *= mask[row + i];
        if constexpr (__is_same(TOUT, u16))
          C[(size_t)(row + i) * N + col] = f2b(v);
        else
          C[(size_t)(row + i) * N + col] = v;
      }
    }
  }
}

// =====================================================================
// Attention per (b,t,h): Q(256x128) x K(32x128)^T -> softmax -> x V.
// q-rmsnorm per row; k-rmsnorm + q_norm_w*k_norm_w folded into staged K.
// qb/kvb/out internal bf16; qw/kw external fp32.
// =====================================================================
__global__ __launch_bounds__(256)
void attn_kernel(const u16* __restrict__ qb, const u16* __restrict__ kvb,
                 const float* __restrict__ qw, const float* __restrict__ kw,
                 u16* __restrict__ attnb)
{
  __shared__ __align__(16) float Ks[32][128];
  __shared__ __align__(16) u32 Vsu[32][64];
  __shared__ float scL[256 * 33];
  const int tid = threadIdx.x;
  const int h = blockIdx.x % 24;
  const int bt = blockIdx.x / 24;

  { // stage K (rmsnorm + folded q/k norm weights) and V: 8 threads/row
    const int n = tid >> 3, sub = tid & 7;
    const size_t base = (size_t)(bt * 32 + n) * 6144 + (size_t)h * 128;
    const u16* kp = kvb + base + sub * 16;
    const u16* vp = kvb + base + 3072 + sub * 16;
    float kv_[16]; float ss = 0.f;
    u16x8 k0 = *(const u16x8*)kp;
    u16x8 k1 = *(const u16x8*)(kp + 8);
    #pragma unroll
    for (int j = 0; j < 8; ++j) { kv_[j] = b2f(k0[j]); kv_[8 + j] = b2f(k1[j]); }
    #pragma unroll
    for (int j = 0; j < 16; ++j) ss += kv_[j] * kv_[j];
    ss += __shfl_xor(ss, 1); ss += __shfl_xor(ss, 2); ss += __shfl_xor(ss, 4);
    const float krs = rsqrtf(ss * (1.f / 128.f) + 1e-6f);
    #pragma unroll
    for (int j = 0; j < 16; ++j) {
      const int d = sub * 16 + j;
      Ks[n][d] = kv_[j] * krs * kw[d] * qw[d];
    }
    u32x4 v0 = *(const u32x4*)vp;
    u32x4 v1 = *(const u32x4*)(vp + 8);
    #pragma unroll
    for (int j = 0; j < 4; ++j) { Vsu[n][sub * 8 + j] = v0[j]; Vsu[n][sub * 8 + 4 + j] = v1[j]; }
  }
  __syncthreads();

  const u16* qp = qb + (size_t)(bt * 256 + tid) * 3072 + (size_t)h * 128;
  u32 qr[64]; float qss = 0.f;
  #pragma unroll
  for (int i = 0; i < 16; ++i) {
    u32x4 t = ((const u32x4*)qp)[i];
    qr[4 * i + 0] = t.x; qr[4 * i + 1] = t.y; qr[4 * i + 2] = t.z; qr[4 * i + 3] = t.w;
  }
  #pragma unroll
  for (int i = 0; i < 64; ++i) { const float a = blo(qr[i]), b = bhi(qr[i]); qss += a * a + b * b; }
  const float qsc = rsqrtf(qss * (1.f / 128.f) + 1e-6f) * 0.08838834764831845f; // * 1/sqrt(D)

  float* mysc = &scL[tid * 33];
  for (int n2 = 0; n2 < 32; ++n2) {
    const f32x4* kr = (const f32x4*)&Ks[n2][0];
    float dot = 0.f;
    #pragma unroll
    for (int dd = 0; dd < 32; ++dd) {
      const f32x4 kk = kr[dd];
      const u32 a0 = qr[2 * dd], a1 = qr[2 * dd + 1];
      dot += blo(a0) * kk.x + bhi(a0) * kk.y + blo(a1) * kk.z + bhi(a1) * kk.w;
    }
    mysc[n2] = dot * qsc;
  }

  float p[32];
  #pragma unroll
  for (int j = 0; j < 32; ++j) p[j] = mysc[j];
  float mx = p[0];
  #pragma unroll
  for (int j = 1; j < 32; ++j) mx = fmaxf(mx, p[j]);
  float se = 0.f;
  #pragma unroll
  for (int j = 0; j < 32; ++j) { p[j] = expf(p[j] - mx); se += p[j]; }
  const float inv = 1.f / se;
  #pragma unroll
  for (int j = 0; j < 32; ++j) mysc[j] = p[j] * inv;

  u16* op = attnb + (size_t)(bt * 256 + tid) * 3072 + (size_t)h * 128;
  for (int db = 0; db < 16; ++db) {
    float o[8] = {0.f, 0.f, 0.f, 0.f, 0.f, 0.f, 0.f, 0.f};
    for (int n2 = 0; n2 < 32; ++n2) {
      const u32x4 vv = *(const u32x4*)&Vsu[n2][db * 4];
      const float pp = mysc[n2];
      o[0] += pp * blo(vv.x); o[1] += pp * bhi(vv.x);
      o[2] += pp * blo(vv.y); o[3] += pp * bhi(vv.y);
      o[4] += pp * blo(vv.z); o[5] += pp * bhi(vv.z);
      o[6] += pp * blo(vv.w); o[7] += pp * bhi(vv.w);
    }
    u16x8 w;
    #pragma unroll
    for (int j = 0; j < 8; ++j) w[j] = f2b(o[j]);
    *(u16x8*)(op + db * 8) = w;
  }
}

// =====================================================================
extern "C" void kernel_launch(void* const* d_in, const int* in_sizes, int n_in,
                              void* d_out, int out_size, void* d_ws, size_t ws_size,
                              hipStream_t stream) {
  const float* x    = (const float*)d_in[0];
  const float* mv   = (const float*)d_in[1];
  const float* mask = (const float*)d_in[2];
  const float* wkv  = (const float*)d_in[3];
  const float* bkv  = (const float*)d_in[4];
  const float* wq   = (const float*)d_in[5];
  const float* bq   = (const float*)d_in[6];
  const float* wo   = (const float*)d_in[7];
  const float* bo   = (const float*)d_in[8];
  const float* qnw  = (const float*)d_in[9];
  const float* knw  = (const float*)d_in[10];
  float* out = (float*)d_out;

  char* ws = (char*)d_ws;
  u16* xf   = (u16*)(ws);                 // 8192x3072 bf16 = 50,331,648 B
  u16* xm   = (u16*)(ws + 50331648);      // 1024x3072 bf16 =  6,291,456 B
  u16* qbuf = (u16*)(ws + 56623104);      // 8192x3072 bf16 = 50,331,648 B
  u16* kvb  = (u16*)(ws + 106954752);     // 1024x6144 bf16 = 12,582,912 B (end 119,537,664)
  u16* wslab = (u16*)(ws + 119537664);    // up to 6144x3072 bf16 = 37,748,736 B (end 157,286,400)

  ln_kernel<<<9216, 256, 0, stream>>>(x, mv, xf, xm);

  if (ws_size >= 157286400u) {
    // pre-converted bf16 weights, pure m97 GEMMs
    wcvt_kernel<<<2048, 256, 0, stream>>>(wq, wslab, 3072 * 3072 / 4);
    gemm_bb<0, u16><<<1536, 256, 0, stream>>>(xf, wslab, bq, nullptr, qbuf, 8192, 3072, 3072);
    wcvt_kernel<<<2048, 256, 0, stream>>>(wkv, wslab, 6144 * 3072 / 4);
    gemm_bb<0, u16><<<384, 256, 0, stream>>>(xm, wslab, bkv, nullptr, kvb, 1024, 6144, 3072);
    attn_kernel<<<768, 256, 0, stream>>>(qbuf, kvb, qnw, knw, xf);
    wcvt_kernel<<<2048, 256, 0, stream>>>(wo, wslab, 3072 * 3072 / 4);
    gemm_bb<1, float><<<1536, 256, 0, stream>>>(xf, wslab, bo, mask, out, 8192, 3072, 3072);
  } else {
    // fallback: on-the-fly fp32 weight conversion inside GEMM (R3 path)
    gemm_mixed<0, u16><<<1536, 256, 0, stream>>>(xf, wq, bq, nullptr, qbuf, 8192, 3072, 3072);
    gemm_mixed<0, u16><<<384, 256, 0, stream>>>(xm, wkv, bkv, nullptr, kvb, 1024, 6144, 3072);
    attn_kernel<<<768, 256, 0, stream>>>(qbuf, kvb, qnw, knw, xf);
    gemm_mixed<1, float><<<1536, 256, 0, stream>>>(xf, wo, bo, mask, out, 8192, 3072, 3072);
  }
}

// Round 5
// 567.425 us; speedup vs baseline: 1.4364x; 1.1736x over previous
//
#include <hip/hip_runtime.h>
#include <math.h>

typedef unsigned short u16;
typedef unsigned int u32;
typedef short bf16x8 __attribute__((ext_vector_type(8)));
typedef float f32x4 __attribute__((ext_vector_type(4)));
typedef u16 u16x4 __attribute__((ext_vector_type(4)));
typedef u16 u16x8 __attribute__((ext_vector_type(8)));
typedef u32 u32x4 __attribute__((ext_vector_type(4)));

// ---------- bf16 <-> f32 helpers ----------
static __device__ __forceinline__ float b2f(u16 u) {
  union { u32 i; float f; } v; v.i = ((u32)u) << 16; return v.f;
}
static __device__ __forceinline__ float blo(u32 u) {
  union { u32 i; float f; } v; v.i = u << 16; return v.f;
}
static __device__ __forceinline__ float bhi(u32 u) {
  union { u32 i; float f; } v; v.i = u & 0xffff0000u; return v.f;
}
static __device__ __forceinline__ u16 f2b(float f) {
  union { float f; u32 i; } v; v.f = f;
  u32 r = v.i + 0x7fffu + ((v.i >> 16) & 1u);
  return (u16)(r >> 16);
}

// ---------- async global -> LDS, 16B per lane ----------
static __device__ __forceinline__ void g2l16(const void* g, void* l) {
  typedef __attribute__((address_space(1))) const void gvoid;
  typedef __attribute__((address_space(3))) void lvoid;
  __builtin_amdgcn_global_load_lds((gvoid*)g, (lvoid*)l, 16, 0, 0);
}

// =====================================================================
// Weight convert: fp32 -> bf16, grid-stride.
// =====================================================================
__global__ __launch_bounds__(256)
void wcvt_kernel(const float* __restrict__ src, u16* __restrict__ dst, int n4)
{
  for (int i = blockIdx.x * 256 + threadIdx.x; i < n4; i += gridDim.x * 256) {
    f32x4 v = *(const f32x4*)(src + (size_t)i * 4);
    u16x4 w; w.x = f2b(v.x); w.y = f2b(v.y); w.z = f2b(v.z); w.w = f2b(v.w);
    *(u16x4*)(dst + (size_t)i * 4) = w;
  }
}

// =====================================================================
// LayerNorm: rows 0..8191 -> x_feat (x), rows 8192..9215 -> x_motion (mv).
// C = 3072, no affine. fp32 in -> bf16 out.
// =====================================================================
__global__ __launch_bounds__(256)
void ln_kernel(const float* __restrict__ x, const float* __restrict__ mv,
               u16* __restrict__ xf, u16* __restrict__ xm)
{
  const int row = blockIdx.x, tid = threadIdx.x;
  const float* src; u16* dst;
  if (row < 8192) { src = x + (size_t)row * 3072;          dst = xf + (size_t)row * 3072; }
  else            { src = mv + (size_t)(row - 8192) * 3072; dst = xm + (size_t)(row - 8192) * 3072; }

  f32x4 vals[3];
  #pragma unroll
  for (int i = 0; i < 3; ++i) vals[i] = *(const f32x4*)(src + tid * 4 + i * 1024);

  float s1 = 0.f, s2 = 0.f;
  #pragma unroll
  for (int i = 0; i < 3; ++i) {
    f32x4 v = vals[i];
    s1 += v.x + v.y + v.z + v.w;
    s2 += v.x * v.x + v.y * v.y + v.z * v.z + v.w * v.w;
  }
  #pragma unroll
  for (int o = 32; o > 0; o >>= 1) { s1 += __shfl_down(s1, o); s2 += __shfl_down(s2, o); }
  __shared__ float r1[4], r2[4];
  const int wv = tid >> 6, ln = tid & 63;
  if (ln == 0) { r1[wv] = s1; r2[wv] = s2; }
  __syncthreads();
  const float t1 = r1[0] + r1[1] + r1[2] + r1[3];
  const float t2 = r2[0] + r2[1] + r2[2] + r2[3];
  const float mu = t1 * (1.f / 3072.f);
  const float rs = rsqrtf(t2 * (1.f / 3072.f) - mu * mu + 1e-6f);
  #pragma unroll
  for (int i = 0; i < 3; ++i) {
    f32x4 v = vals[i]; u16x4 w;
    w.x = f2b((v.x - mu) * rs); w.y = f2b((v.y - mu) * rs);
    w.z = f2b((v.z - mu) * rs); w.w = f2b((v.w - mu) * rs);
    *(u16x4*)(dst + tid * 4 + i * 1024) = w;
  }
}

// =====================================================================
// Pipelined GEMM: C[M,N] = A[M,K] @ Wb[N,K]^T + bias[N]  (bf16 x bf16)
// 256x128 tile, BK=32, 4 waves (2x2), per-wave 128x64 output.
// 3-buffer LDS rotation, counted s_waitcnt vmcnt(6) + raw s_barrier
// (never drain-to-0 in loop), XOR-swizzled LDS via pre-swizzled global
// source (linear global_load_lds dest), setprio around MFMA cluster,
// XCD-aware block swizzle. EPI==1: multiply rows by fp32 mask[row].
// =====================================================================
template<int EPI, typename TOUT>
__global__ __launch_bounds__(256, 2)
void gemm256(const u16* __restrict__ A, const u16* __restrict__ Wb,
             const float* __restrict__ bias, const float* __restrict__ mask,
             TOUT* __restrict__ C, int M, int N, int K)
{
  // 3 bufs x (A 256x32 @0 + B 128x32 @8192) u16 = 36864 u16 = 72 KB
  __shared__ __align__(16) u16 L[36864];
  const int tid = threadIdx.x, wave = tid >> 6, lane = tid & 63;

  // XCD-aware bijective swizzle (gridDim.x % 8 == 0 for all our shapes)
  const int nwg = gridDim.x;
  const int bid = (blockIdx.x & 7) * (nwg >> 3) + (blockIdx.x >> 3);
  const int nbx = N >> 7;
  const int brow = (bid / nbx) << 8;
  const int bcol = (bid % nbx) << 7;
  const int wr = wave >> 1, wc = wave & 1;

  const u16* gA = A + (size_t)brow * K;
  const u16* gB = Wb + (size_t)bcol * K;

  // staging constants: round = 256 thr x 16B = 64 rows (row = 64B)
  const int srow = tid >> 2;                               // row within round
  const int scol = 8 * ((lane & 3) ^ ((lane >> 3) & 3));   // pre-swizzled src col (elems)
  // read swizzle: phys col = logical k-group ^ ((row>>1)&3), in 8-elem slots
  const int rcoff = 8 * ((lane >> 4) ^ ((lane >> 1) & 3));

  f32x4 acc[8][4] = {};

  auto STAGE = [&](int b, int tk) {
    u16* bufA = &L[b * 12288];
    u16* bufB = bufA + 8192;
    const u16* srcA = gA + tk + scol;
    const u16* srcB = gB + tk + scol;
    #pragma unroll
    for (int j = 0; j < 4; ++j)   // A: 256 rows = 4 rounds
      g2l16(srcA + (size_t)(j * 64 + srow) * K, bufA + (j * 64 + wave * 16) * 32);
    #pragma unroll
    for (int j = 0; j < 2; ++j)   // B: 128 rows = 2 rounds
      g2l16(srcB + (size_t)(j * 64 + srow) * K, bufB + (j * 64 + wave * 16) * 32);
  };

  auto COMPUTE = [&](int b) {
    const u16* bufA = &L[b * 12288];
    const u16* bufB = bufA + 8192;
    bf16x8 af[8], bfv[4];
    #pragma unroll
    for (int m = 0; m < 8; ++m)
      af[m] = *(const bf16x8*)&bufA[(wr * 128 + m * 16 + (lane & 15)) * 32 + rcoff];
    #pragma unroll
    for (int n = 0; n < 4; ++n)
      bfv[n] = *(const bf16x8*)&bufB[(wc * 64 + n * 16 + (lane & 15)) * 32 + rcoff];
    __builtin_amdgcn_s_setprio(1);
    #pragma unroll
    for (int m = 0; m < 8; ++m)
      #pragma unroll
      for (int n = 0; n < 4; ++n)
        acc[m][n] = __builtin_amdgcn_mfma_f32_16x16x32_bf16(af[m], bfv[n], acc[m][n], 0, 0, 0);
    __builtin_amdgcn_s_setprio(0);
  };

  // prologue: stage tiles 0 and 1 (12 loads out), wait for tile 0 (6 remain)
  STAGE(0, 0);
  STAGE(1, 32);
  asm volatile("s_waitcnt vmcnt(6)" ::: "memory");
  __builtin_amdgcn_s_barrier();
  __builtin_amdgcn_sched_barrier(0);

  const int NT = K >> 5;
  int cur = 0;
  for (int t = 0; t < NT; ++t) {
    const bool pf = (t + 2) < NT;
    if (pf) {
      int nb = cur + 2; if (nb >= 3) nb -= 3;
      STAGE(nb, (t + 2) << 5);   // buffer read at iter t-1: reads done => safe
    }
    COMPUTE(cur);
    // tile t+1's 6 loads are the oldest outstanding: retire them, keep t+2 in flight
    if (pf) asm volatile("s_waitcnt vmcnt(6)" ::: "memory");
    else    asm volatile("s_waitcnt vmcnt(0)" ::: "memory");
    __builtin_amdgcn_s_barrier();
    __builtin_amdgcn_sched_barrier(0);
    if (++cur == 3) cur = 0;
  }

  // epilogue: D row = 4*(lane>>4)+i within 16-block (m89-verified layout)
  #pragma unroll
  for (int m = 0; m < 8; ++m) {
    const int row = brow + wr * 128 + m * 16 + ((lane >> 4) << 2);
    #pragma unroll
    for (int n = 0; n < 4; ++n) {
      const int col = bcol + wc * 64 + n * 16 + (lane & 15);
      const float bv = bias[col];
      #pragma unroll
      for (int i = 0; i < 4; ++i) {
        float v = acc[m][n][i] + bv;
        if (EPI == 1) v *= mask[row + i];
        if constexpr (__is_same(TOUT, u16))
          C[(size_t)(row + i) * N + col] = f2b(v);
        else
          C[(size_t)(row + i) * N + col] = v;
      }
    }
  }
}

// =====================================================================
// Fallback mixed GEMM (R3 path, 128x128): W fp32, reg-staged cvt.
// Used only if ws_size too small for the weight slab (not expected).
// =====================================================================
template<int EPI, typename TOUT>
__global__ __launch_bounds__(256)
void gemm_mixed(const u16* __restrict__ A, const float* __restrict__ W,
                const float* __restrict__ bias, const float* __restrict__ mask,
                TOUT* __restrict__ C, int M, int N, int K)
{
  __shared__ __align__(16) u16 lA[4096];
  __shared__ __align__(16) u16 lB[4096];
  const int tid = threadIdx.x, wave = tid >> 6, lane = tid & 63;
  const int nbx = N >> 7;
  const int brow = (blockIdx.x / nbx) << 7;
  const int bcol = (blockIdx.x % nbx) << 7;
  const int wr = wave >> 1, wc = wave & 1;

  f32x4 acc[4][4] = {};
  const u16* gA = A + (size_t)brow * K;
  const float* gB = W + (size_t)bcol * K;
  const int br = tid >> 1, bk0 = (tid & 1) << 4;
  const float* bsrc0 = gB + (size_t)br * K + bk0;
  u16* bdst = &lB[br * 32 + bk0];

  for (int tk = 0; tk < K; tk += 32) {
    #pragma unroll
    for (int j = 0; j < 2; ++j) {
      const int c = j * 256 + wave * 64 + lane;
      const int r = c >> 2, k8 = (c & 3) << 3;
      g2l16(gA + (size_t)r * K + tk + k8, (char*)lA + (size_t)(j * 256 + wave * 64) * 16);
    }
    {
      const float* src = bsrc0 + tk;
      #pragma unroll
      for (int j = 0; j < 4; ++j) {
        f32x4 v = *(const f32x4*)(src + 4 * j);
        u16x4 w; w.x = f2b(v.x); w.y = f2b(v.y); w.z = f2b(v.z); w.w = f2b(v.w);
        *(u16x4*)(bdst + 4 * j) = w;
      }
    }
    __syncthreads();

    bf16x8 af[4], bfr[4];
    #pragma unroll
    for (int m = 0; m < 4; ++m)
      af[m] = *(const bf16x8*)&lA[(wr * 64 + m * 16 + (lane & 15)) * 32 + ((lane >> 4) << 3)];
    #pragma unroll
    for (int n = 0; n < 4; ++n)
      bfr[n] = *(const bf16x8*)&lB[(wc * 64 + n * 16 + (lane & 15)) * 32 + ((lane >> 4) << 3)];
    #pragma unroll
    for (int m = 0; m < 4; ++m)
      #pragma unroll
      for (int n = 0; n < 4; ++n)
        acc[m][n] = __builtin_amdgcn_mfma_f32_16x16x32_bf16(af[m], bfr[n], acc[m][n], 0, 0, 0);
    __syncthreads();
  }

  #pragma unroll
  for (int m = 0; m < 4; ++m) {
    const int row = brow + wr * 64 + m * 16 + ((lane >> 4) << 2);
    #pragma unroll
    for (int n = 0; n < 4; ++n) {
      const int col = bcol + wc * 64 + n * 16 + (lane & 15);
      const float bv = bias[col];
      #pragma unroll
      for (int i = 0; i < 4; ++i) {
        float v = acc[m][n][i] + bv;
        if (EPI == 1) v *= mask[row + i];
        if constexpr (__is_same(TOUT, u16))
          C[(size_t)(row + i) * N + col] = f2b(v);
        else
          C[(size_t)(row + i) * N + col] = v;
      }
    }
  }
}

// =====================================================================
// Attention per (b,t,h): Q(256x128) x K(32x128)^T -> softmax -> x V.
// q-rmsnorm per row; k-rmsnorm + q_norm_w*k_norm_w folded into staged K.
// =====================================================================
__global__ __launch_bounds__(256)
void attn_kernel(const u16* __restrict__ qb, const u16* __restrict__ kvb,
                 const float* __restrict__ qw, const float* __restrict__ kw,
                 u16* __restrict__ attnb)
{
  __shared__ __align__(16) float Ks[32][128];
  __shared__ __align__(16) u32 Vsu[32][64];
  __shared__ float scL[256 * 33];
  const int tid = threadIdx.x;
  const int h = blockIdx.x % 24;
  const int bt = blockIdx.x / 24;

  {
    const int n = tid >> 3, sub = tid & 7;
    const size_t base = (size_t)(bt * 32 + n) * 6144 + (size_t)h * 128;
    const u16* kp = kvb + base + sub * 16;
    const u16* vp = kvb + base + 3072 + sub * 16;
    float kv_[16]; float ss = 0.f;
    u16x8 k0 = *(const u16x8*)kp;
    u16x8 k1 = *(const u16x8*)(kp + 8);
    #pragma unroll
    for (int j = 0; j < 8; ++j) { kv_[j] = b2f(k0[j]); kv_[8 + j] = b2f(k1[j]); }
    #pragma unroll
    for (int j = 0; j < 16; ++j) ss += kv_[j] * kv_[j];
    ss += __shfl_xor(ss, 1); ss += __shfl_xor(ss, 2); ss += __shfl_xor(ss, 4);
    const float krs = rsqrtf(ss * (1.f / 128.f) + 1e-6f);
    #pragma unroll
    for (int j = 0; j < 16; ++j) {
      const int d = sub * 16 + j;
      Ks[n][d] = kv_[j] * krs * kw[d] * qw[d];
    }
    u32x4 v0 = *(const u32x4*)vp;
    u32x4 v1 = *(const u32x4*)(vp + 8);
    #pragma unroll
    for (int j = 0; j < 4; ++j) { Vsu[n][sub * 8 + j] = v0[j]; Vsu[n][sub * 8 + 4 + j] = v1[j]; }
  }
  __syncthreads();

  const u16* qp = qb + (size_t)(bt * 256 + tid) * 3072 + (size_t)h * 128;
  u32 qr[64]; float qss = 0.f;
  #pragma unroll
  for (int i = 0; i < 16; ++i) {
    u32x4 t = ((const u32x4*)qp)[i];
    qr[4 * i + 0] = t.x; qr[4 * i + 1] = t.y; qr[4 * i + 2] = t.z; qr[4 * i + 3] = t.w;
  }
  #pragma unroll
  for (int i = 0; i < 64; ++i) { const float a = blo(qr[i]), b = bhi(qr[i]); qss += a * a + b * b; }
  const float qsc = rsqrtf(qss * (1.f / 128.f) + 1e-6f) * 0.08838834764831845f;

  float* mysc = &scL[tid * 33];
  for (int n2 = 0; n2 < 32; ++n2) {
    const f32x4* kr = (const f32x4*)&Ks[n2][0];
    float dot = 0.f;
    #pragma unroll
    for (int dd = 0; dd < 32; ++dd) {
      const f32x4 kk = kr[dd];
      const u32 a0 = qr[2 * dd], a1 = qr[2 * dd + 1];
      dot += blo(a0) * kk.x + bhi(a0) * kk.y + blo(a1) * kk.z + bhi(a1) * kk.w;
    }
    mysc[n2] = dot * qsc;
  }

  float p[32];
  #pragma unroll
  for (int j = 0; j < 32; ++j) p[j] = mysc[j];
  float mx = p[0];
  #pragma unroll
  for (int j = 1; j < 32; ++j) mx = fmaxf(mx, p[j]);
  float se = 0.f;
  #pragma unroll
  for (int j = 0; j < 32; ++j) { p[j] = expf(p[j] - mx); se += p[j]; }
  const float inv = 1.f / se;
  #pragma unroll
  for (int j = 0; j < 32; ++j) mysc[j] = p[j] * inv;

  u16* op = attnb + (size_t)(bt * 256 + tid) * 3072 + (size_t)h * 128;
  for (int db = 0; db < 16; ++db) {
    float o[8] = {0.f, 0.f, 0.f, 0.f, 0.f, 0.f, 0.f, 0.f};
    for (int n2 = 0; n2 < 32; ++n2) {
      const u32x4 vv = *(const u32x4*)&Vsu[n2][db * 4];
      const float pp = mysc[n2];
      o[0] += pp * blo(vv.x); o[1] += pp * bhi(vv.x);
      o[2] += pp * blo(vv.y); o[3] += pp * bhi(vv.y);
      o[4] += pp * blo(vv.z); o[5] += pp * bhi(vv.z);
      o[6] += pp * blo(vv.w); o[7] += pp * bhi(vv.w);
    }
    u16x8 w;
    #pragma unroll
    for (int j = 0; j < 8; ++j) w[j] = f2b(o[j]);
    *(u16x8*)(op + db * 8) = w;
  }
}

// =====================================================================
extern "C" void kernel_launch(void* const* d_in, const int* in_sizes, int n_in,
                              void* d_out, int out_size, void* d_ws, size_t ws_size,
                              hipStream_t stream) {
  const float* x    = (const float*)d_in[0];
  const float* mv   = (const float*)d_in[1];
  const float* mask = (const float*)d_in[2];
  const float* wkv  = (const float*)d_in[3];
  const float* bkv  = (const float*)d_in[4];
  const float* wq   = (const float*)d_in[5];
  const float* bq   = (const float*)d_in[6];
  const float* wo   = (const float*)d_in[7];
  const float* bo   = (const float*)d_in[8];
  const float* qnw  = (const float*)d_in[9];
  const float* knw  = (const float*)d_in[10];
  float* out = (float*)d_out;

  char* ws = (char*)d_ws;
  u16* xf   = (u16*)(ws);                 // 8192x3072 bf16
  u16* xm   = (u16*)(ws + 50331648);      // 1024x3072 bf16
  u16* qbuf = (u16*)(ws + 56623104);      // 8192x3072 bf16
  u16* kvb  = (u16*)(ws + 106954752);     // 1024x6144 bf16
  u16* wslab = (u16*)(ws + 119537664);    // up to 6144x3072 bf16 (end 157,286,400)

  ln_kernel<<<9216, 256, 0, stream>>>(x, mv, xf, xm);

  if (ws_size >= 157286400u) {
    wcvt_kernel<<<2048, 256, 0, stream>>>(wq, wslab, 3072 * 3072 / 4);
    gemm256<0, u16><<<768, 256, 0, stream>>>(xf, wslab, bq, nullptr, qbuf, 8192, 3072, 3072);
    wcvt_kernel<<<2048, 256, 0, stream>>>(wkv, wslab, 6144 * 3072 / 4);
    gemm256<0, u16><<<192, 256, 0, stream>>>(xm, wslab, bkv, nullptr, kvb, 1024, 6144, 3072);
    attn_kernel<<<768, 256, 0, stream>>>(qbuf, kvb, qnw, knw, xf);
    wcvt_kernel<<<2048, 256, 0, stream>>>(wo, wslab, 3072 * 3072 / 4);
    gemm256<1, float><<<768, 256, 0, stream>>>(xf, wslab, bo, mask, out, 8192, 3072, 3072);
  } else {
    gemm_mixed<0, u16><<<1536, 256, 0, stream>>>(xf, wq, bq, nullptr, qbuf, 8192, 3072, 3072);
    gemm_mixed<0, u16><<<384, 256, 0, stream>>>(xm, wkv, bkv, nullptr, kvb, 1024, 6144, 3072);
    attn_kernel<<<768, 256, 0, stream>>>(qbuf, kvb, qnw, knw, xf);
    gemm_mixed<1, float><<<1536, 256, 0, stream>>>(xf, wo, bo, mask, out, 8192, 3072, 3072);
  }
}